// Round 2
// baseline (1666.336 us; speedup 1.0000x reference)
//
#include <hip/hip_runtime.h>
#include <stdint.h>

#define NN 50000
#define NE 800000
#define M_PAD 50176   // 196 * 256

typedef __attribute__((ext_vector_type(8))) short short8;
typedef __attribute__((ext_vector_type(4))) float f32x4;

static __device__ __forceinline__ float bf2f(unsigned short v) {
    union { unsigned u; float f; } c; c.u = ((unsigned)v) << 16; return c.f;
}
static __device__ __forceinline__ unsigned short f2bf(float f) {
    union { float f; unsigned u; } c; c.f = f;
    unsigned u = c.u;
    u += 0x7fffu + ((u >> 16) & 1u);   // RNE, inputs finite
    return (unsigned short)(u >> 16);
}

// ---------------- elementwise converters ----------------
__global__ void f32_to_bf16_k(const float* __restrict__ in, unsigned short* __restrict__ out, long n4) {
    long i = (long)blockIdx.x * 256 + threadIdx.x;
    if (i >= n4) return;
    float4 v = ((const float4*)in)[i];
    ushort4 o; o.x = f2bf(v.x); o.y = f2bf(v.y); o.z = f2bf(v.z); o.w = f2bf(v.w);
    ((ushort4*)out)[i] = o;
}
// W (K x N f32) -> Wt (N x K bf16). i = n*K + k (k fast => coalesced writes).
__global__ void wt_k(const float* __restrict__ w, unsigned short* __restrict__ wt, int K, int N) {
    int i = blockIdx.x * 256 + threadIdx.x;
    if (i >= K * N) return;
    int k = i % K, n = i / K;
    wt[i] = f2bf(w[(long)k * N + n]);
}

// ---------------- CSR build ----------------
__global__ void zero_k(int* __restrict__ p, int n) {
    int i = blockIdx.x * 256 + threadIdx.x;
    if (i < n) p[i] = 0;
}
__global__ void hist_k(const int* __restrict__ ei, int* __restrict__ deg) {
    int e = blockIdx.x * 256 + threadIdx.x;
    if (e >= NE) return;
    atomicAdd(&deg[ei[NE + e]], 1);
}
// single-block exclusive scan over deg[NN] -> row_ptr, cursor
__global__ __launch_bounds__(1024)
void scan_k(const int* __restrict__ deg, int* __restrict__ row_ptr, int* __restrict__ cursor) {
    constexpr int T = 1024, C = (NN + T - 1) / T;  // 49
    const int tid = threadIdx.x;
    const int base = tid * C;
    int s = 0;
#pragma unroll 4
    for (int i = 0; i < C; ++i) {
        int idx = base + i;
        if (idx < NN) s += deg[idx];
    }
    __shared__ int sm[T];
    sm[tid] = s;
    __syncthreads();
    for (int off = 1; off < T; off <<= 1) {
        int v = (tid >= off) ? sm[tid - off] : 0;
        __syncthreads();
        sm[tid] += v;
        __syncthreads();
    }
    int run = (tid == 0) ? 0 : sm[tid - 1];
#pragma unroll 4
    for (int i = 0; i < C; ++i) {
        int idx = base + i;
        if (idx < NN) {
            row_ptr[idx] = run;
            cursor[idx] = run;
            run += deg[idx];
        }
    }
}
__global__ void build_col_k(const int* __restrict__ ei, int* __restrict__ cursor, int* __restrict__ col) {
    int e = blockIdx.x * 256 + threadIdx.x;
    if (e >= NE) return;
    int d = ei[NE + e];
    int p = atomicAdd(&cursor[d], 1);
    col[p] = ei[e];
}

// ---------------- gather-aggregate: z[n] = h[n] + sum_{j->n} h[j], bf16 out ----------------
template <int V> struct VecT;
template <> struct VecT<2> { using T = unsigned int; };
template <> struct VecT<4> { using T = uint2; };
template <> struct VecT<8> { using T = uint4; };

template <int D>
__global__ __launch_bounds__(256)
void agg_gather_k(const unsigned short* __restrict__ h,
                  const int* __restrict__ row_ptr, const int* __restrict__ deg,
                  const int* __restrict__ col, unsigned short* __restrict__ z) {
    constexpr int V = D / 64;
    using VT = typename VecT<V>::T;
    union U { VT v; unsigned short s[V]; };
    const int node = blockIdx.x * 4 + (threadIdx.x >> 6);
    if (node >= NN) return;
    const int lane = threadIdx.x & 63;
    const size_t fb = (size_t)lane * V;

    float acc[V];
    {
        U b; b.v = *(const VT*)(h + (size_t)node * D + fb);
#pragma unroll
        for (int i = 0; i < V; ++i) acc[i] = bf2f(b.s[i]);
    }
    const int s = row_ptr[node];
    const int e = s + deg[node];
    int t = s;
    for (; t + 2 <= e; t += 2) {
        int s0 = col[t], s1 = col[t + 1];
        U a0, a1;
        a0.v = *(const VT*)(h + (size_t)s0 * D + fb);
        a1.v = *(const VT*)(h + (size_t)s1 * D + fb);
#pragma unroll
        for (int i = 0; i < V; ++i) acc[i] += bf2f(a0.s[i]);
#pragma unroll
        for (int i = 0; i < V; ++i) acc[i] += bf2f(a1.s[i]);
    }
    if (t < e) {
        U a; a.v = *(const VT*)(h + (size_t)col[t] * D + fb);
#pragma unroll
        for (int i = 0; i < V; ++i) acc[i] += bf2f(a.s[i]);
    }
    U o;
#pragma unroll
    for (int i = 0; i < V; ++i) o.s[i] = f2bf(acc[i]);
    *(VT*)(z + (size_t)node * D + fb) = o.v;
}

// ---------------- 8-phase MFMA GEMM (T3+T4 counted vmcnt, T2 swizzle, T5 setprio) ----------------
// BM=256, BN=128, BK=64. 512 threads = 8 waves as 4M x 2N. per-wave 64x64 out.
// LDS: 2 x (A 256x64 + B 128x64) bf16 = 96 KiB -> 1 block/CU, 8 waves.
// XOR swizzle folded into the per-lane global SOURCE address: LDS slot s of row r
// holds k-block (s ^ (r&7)); fragment reads use the same XOR -> 0 bank conflicts.

// stage one 8-row x 64-col group (1 KiB per wave; 1 instr/thread)
static __device__ __forceinline__ void stg(const unsigned short* src, int rstride,
                                           unsigned short* ldsb, int row8, int lane) {
    const int row = row8 + (lane >> 3);
    const int kblk = (lane & 7) ^ (row & 7);
    __builtin_amdgcn_global_load_lds(
        (const __attribute__((address_space(1))) void*)(src + (size_t)row * rstride + (size_t)kblk * 8),
        (__attribute__((address_space(3))) void*)(ldsb + row8 * 64),
        16, 0, 0);
}

#define G_BAR asm volatile("s_barrier" ::: "memory")
#define WAITV(n) asm volatile("s_waitcnt vmcnt(" #n ")" ::: "memory")

// A-lo group g in 0..15 -> rows (g>>2)*64 + (g&3)*8 .. +7  (per-64 row-block rows 0..31)
#define ALO_ROW8(g) ((((g) >> 2) << 6) + (((g) & 3) << 3))
#define AHI_ROW8(g) (ALO_ROW8(g) + 32)

#define PHASE_LOAD(BUF, Q)                                                         \
    short8 aF[2][2], bF[4][2];                                                     \
    _Pragma("unroll") for (int kk = 0; kk < 2; ++kk) {                             \
        const int kb = kk * 4 + quad;                                              \
        _Pragma("unroll") for (int m2 = 0; m2 < 2; ++m2) {                         \
            const int ml = wm * 64 + ((Q) * 2 + m2) * 16 + l15;                    \
            aF[m2][kk] = *(const short8*)&lA[BUF][(ml * 8 + (kb ^ (ml & 7))) * 8]; \
        }                                                                          \
        _Pragma("unroll") for (int nj = 0; nj < 4; ++nj) {                         \
            const int nl = wn * 64 + nj * 16 + l15;                                \
            bF[nj][kk] = *(const short8*)&lB[BUF][(nl * 8 + (kb ^ (nl & 7))) * 8]; \
        }                                                                          \
    }

#define PHASE_MFMA(Q)                                                              \
    __builtin_amdgcn_s_setprio(1);                                                 \
    _Pragma("unroll") for (int m2 = 0; m2 < 2; ++m2)                               \
        _Pragma("unroll") for (int nj = 0; nj < 4; ++nj)                           \
            _Pragma("unroll") for (int kk = 0; kk < 2; ++kk)                       \
                acc[(Q) * 2 + m2][nj] = __builtin_amdgcn_mfma_f32_16x16x32_bf16(   \
                    aF[m2][kk], bF[nj][kk], acc[(Q) * 2 + m2][nj], 0, 0, 0);       \
    __builtin_amdgcn_s_setprio(0);

// FUSED=false: out bf16 = relu(A1*B1t^T + bias1)
// FUSED=true : out f32  = relu( relu(A1*B1t^T + bias1) + A2*B2t^T + bias2 )
template <int K1, int K2, int N, bool FUSED>
__global__ __launch_bounds__(512, 2)
void gemm8_k(const unsigned short* __restrict__ A1, const unsigned short* __restrict__ B1t,
             const float* __restrict__ bias1,
             const unsigned short* __restrict__ A2, const unsigned short* __restrict__ B2t,
             const float* __restrict__ bias2,
             unsigned short* __restrict__ outH, float* __restrict__ outF, int M) {
    constexpr int NT1 = K1 / 64;
    constexpr int NT2 = (K2 > 0) ? K2 / 64 : 0;
    constexpr int NT = NT1 + NT2;
    constexpr int NI = NT / 2;
    static_assert(NT % 2 == 0 && NT >= 2, "NT must be even");
    constexpr int NTn = N / 128;

    __shared__ unsigned short lA[2][256 * 64];   // 64 KiB
    __shared__ unsigned short lB[2][128 * 64];   // 32 KiB

    const int tid = threadIdx.x;
    const int lane = tid & 63;
    const int wid = tid >> 6;
    const int wm = wid >> 1, wn = wid & 1;
    const int l15 = lane & 15, quad = lane >> 4;

    // XCD-aware bijective swizzle (m204), m-major logical order for A-panel L2 reuse
    int m0, n0;
    {
        const int nwg = NTn * (int)gridDim.y;
        const int orig = (int)(blockIdx.y * gridDim.x + blockIdx.x);
        const int q = nwg >> 3, r = nwg & 7;
        const int xcd = orig & 7, idx = orig >> 3;
        const int logical = (xcd < r ? xcd * (q + 1) : r * (q + 1) + (xcd - r) * q) + idx;
        m0 = (logical / NTn) * 256;
        n0 = (logical % NTn) * 128;
    }

    const unsigned short* baseA1 = A1 + (size_t)m0 * K1;
    const unsigned short* baseB1 = B1t + (size_t)n0 * K1;
    const unsigned short* baseA2 = FUSED ? A2 + (size_t)m0 * K2 : nullptr;
    const unsigned short* baseB2 = FUSED ? B2t + (size_t)n0 * K2 : nullptr;

    // uniform per-tile source select
    auto srcA = [&](int t, const unsigned short*& p, int& st) {
        if (!FUSED || t < NT1) { p = baseA1 + (size_t)t * 64; st = K1; }
        else                   { p = baseA2 + (size_t)(t - NT1) * 64; st = K2; }
    };
    auto srcB = [&](int t, const unsigned short*& p, int& st) {
        if (!FUSED || t < NT1) { p = baseB1 + (size_t)t * 64; st = K1; }
        else                   { p = baseB2 + (size_t)(t - NT1) * 64; st = K2; }
    };

    f32x4 acc[4][4];
#pragma unroll
    for (int i = 0; i < 4; ++i)
#pragma unroll
        for (int j = 0; j < 4; ++j) acc[i][j] = (f32x4){0.f, 0.f, 0.f, 0.f};

    // prefetch mid-bias so no vm-ops pollute vmcnt counting in the loop
    float bmid[4];
    if constexpr (FUSED) {
#pragma unroll
        for (int j = 0; j < 4; ++j) bmid[j] = bias1[n0 + wn * 64 + j * 16 + l15];
    }

    // ---- prologue: tile0 full (A 4 + B 2), tile1 A-lo (2) = 8 instrs in flight ----
    {
        const unsigned short* pa; int sa; srcA(0, pa, sa);
#pragma unroll
        for (int k = 0; k < 4; ++k) stg(pa, sa, &lA[0][0], (k * 8 + wid) * 8, lane);
        const unsigned short* pb; int sb; srcB(0, pb, sb);
#pragma unroll
        for (int k = 0; k < 2; ++k) stg(pb, sb, &lB[0][0], (k * 8 + wid) * 8, lane);
        const unsigned short* pa1; int sa1; srcA(1, pa1, sa1);
        stg(pa1, sa1, &lA[1][0], ALO_ROW8(wid), lane);
        stg(pa1, sa1, &lA[1][0], ALO_ROW8(8 + wid), lane);
    }

    // ---- main loop: 2 K-tiles / iter, 4 phases, counted vmcnt (never 0) ----
    for (int i = 0; i < NI; ++i) {
        const int t0 = 2 * i, t1 = 2 * i + 1;
        const int tc = (t0 + 2 < NT) ? t0 + 2 : NT - 1;   // clamp keeps counts uniform
        const int tc2 = (t1 + 2 < NT) ? t1 + 2 : NT - 1;

        // P0 (switch to buf0): stage buf1.A-hi + buf1.B <- tile t1
        {
            const unsigned short* pa; int sa; srcA(t1, pa, sa);
            stg(pa, sa, &lA[1][0], AHI_ROW8(wid), lane);
            stg(pa, sa, &lA[1][0], AHI_ROW8(8 + wid), lane);
            const unsigned short* pb; int sb; srcB(t1, pb, sb);
            stg(pb, sb, &lB[1][0], wid * 8, lane);
            stg(pb, sb, &lB[1][0], (8 + wid) * 8, lane);
        }
        WAITV(6);   // tile t0's 6 loads landed (newest 6 = P3's A-lo(2) + these 4)
        G_BAR;
        { PHASE_LOAD(0, 0); PHASE_MFMA(0); }
        G_BAR;

        // P1: stage buf0.A-lo <- tile t0+2 (region freed by P0)
        {
            const unsigned short* pa; int sa; srcA(tc, pa, sa);
            stg(pa, sa, &lA[0][0], ALO_ROW8(wid), lane);
            stg(pa, sa, &lA[0][0], ALO_ROW8(8 + wid), lane);
        }
        { PHASE_LOAD(0, 1); G_BAR; PHASE_MFMA(1); }
        G_BAR;

        // P2 (switch to buf1): stage buf0.A-hi + buf0.B[rows 0..63] <- t0+2
        {
            const unsigned short* pa; int sa; srcA(tc, pa, sa);
            stg(pa, sa, &lA[0][0], AHI_ROW8(wid), lane);
            stg(pa, sa, &lA[0][0], AHI_ROW8(8 + wid), lane);
            const unsigned short* pb; int sb; srcB(tc, pb, sb);
            stg(pb, sb, &lB[0][0], wid * 8, lane);
        }
        WAITV(5);   // tile t1's 6 loads landed (newest 5 = P1's 2 + these 3)
        G_BAR;
        { PHASE_LOAD(1, 0); PHASE_MFMA(0); }
        G_BAR;

        // P3: stage buf0.B[rows 64..127] <- t0+2 ; buf1.A-lo <- t1+2
        {
            const unsigned short* pb; int sb; srcB(tc, pb, sb);
            stg(pb, sb, &lB[0][0], (8 + wid) * 8, lane);
            const unsigned short* pa; int sa; srcA(tc2, pa, sa);
            stg(pa, sa, &lA[1][0], ALO_ROW8(wid), lane);
            stg(pa, sa, &lA[1][0], ALO_ROW8(8 + wid), lane);
        }
        { PHASE_LOAD(1, 1); G_BAR; PHASE_MFMA(1); }
        if constexpr (FUSED) {
            if (i == NT1 / 2 - 1) {   // end of K-segment 1: in-register relu + bias1
#pragma unroll
                for (int jj = 0; jj < 4; ++jj)
#pragma unroll
                    for (int ii = 0; ii < 4; ++ii)
#pragma unroll
                        for (int rr = 0; rr < 4; ++rr)
                            acc[ii][jj][rr] = fmaxf(acc[ii][jj][rr] + bmid[jj], 0.f);
            }
        }
        G_BAR;
    }
    WAITV(0);   // drain clamped tail prefetches before LDS goes away

    // ---- epilogue ----
    const float* bfin = FUSED ? bias2 : bias1;
#pragma unroll
    for (int j = 0; j < 4; ++j) {
        const int col = n0 + wn * 64 + j * 16 + l15;
        const float bv = bfin[col];
#pragma unroll
        for (int i = 0; i < 4; ++i) {
#pragma unroll
            for (int r = 0; r < 4; ++r) {
                const int row = m0 + wm * 64 + i * 16 + quad * 4 + r;
                if (row < M) {
                    const float v = fmaxf(acc[i][j][r] + bv, 0.f);
                    if constexpr (FUSED) outF[(size_t)row * N + col] = v;
                    else outH[(size_t)row * N + col] = f2bf(v);
                }
            }
        }
    }
}

// ---------------- LayerNorm: one block per row ----------------
template <int D, bool BF16OUT>
__global__ __launch_bounds__(256)
void ln_k(const float* __restrict__ t, const float* __restrict__ g, const float* __restrict__ b,
          unsigned short* __restrict__ outH, float* __restrict__ outF) {
    constexpr int VPT = D / 256;
    const int row = blockIdx.x;
    const int tid = threadIdx.x;
    const float* tp = t + (size_t)row * D;
    float vals[VPT];
    float s = 0.f, ss = 0.f;
#pragma unroll
    for (int i = 0; i < VPT; ++i) {
        float v = tp[i * 256 + tid];
        vals[i] = v; s += v; ss += v * v;
    }
#pragma unroll
    for (int off = 32; off; off >>= 1) { s += __shfl_down(s, off); ss += __shfl_down(ss, off); }
    __shared__ float ps[4], pss[4];
    int lane = tid & 63, wv = tid >> 6;
    if (lane == 0) { ps[wv] = s; pss[wv] = ss; }
    __syncthreads();
    float st = ps[0] + ps[1] + ps[2] + ps[3];
    float sst = pss[0] + pss[1] + pss[2] + pss[3];
    float mean = st / D;
    float var = sst / D - mean * mean;
    float inv = rsqrtf(var + 1e-5f);
#pragma unroll
    for (int i = 0; i < VPT; ++i) {
        int c = i * 256 + tid;
        float o = (vals[i] - mean) * inv * g[c] + b[c];
        if (BF16OUT) outH[(size_t)row * D + c] = f2bf(o);
        else outF[(size_t)row * D + c] = o;
    }
}

static inline int cdiv(long a, long b) { return (int)((a + b - 1) / b); }

extern "C" void kernel_launch(void* const* d_in, const int* in_sizes, int n_in,
                              void* d_out, int out_size, void* d_ws, size_t ws_size,
                              hipStream_t stream) {
    const float* x   = (const float*)d_in[0];
    const int*   ei  = (const int*)  d_in[1];
    const float* w1a = (const float*)d_in[2],  *b1a = (const float*)d_in[3];
    const float* w1b = (const float*)d_in[4],  *b1b = (const float*)d_in[5];
    const float* w2a = (const float*)d_in[6],  *b2a = (const float*)d_in[7];
    const float* w2b = (const float*)d_in[8],  *b2b = (const float*)d_in[9];
    const float* w3a = (const float*)d_in[10], *b3a = (const float*)d_in[11];
    const float* w3b = (const float*)d_in[12], *b3b = (const float*)d_in[13];
    const float* rp1 = (const float*)d_in[14], *rp1b = (const float*)d_in[15];
    const float* rp2 = (const float*)d_in[16], *rp2b = (const float*)d_in[17];
    const float* rp3 = (const float*)d_in[18], *rp3b = (const float*)d_in[19];
    const float* g1 = (const float*)d_in[20], *be1 = (const float*)d_in[21];
    const float* g2 = (const float*)d_in[22], *be2 = (const float*)d_in[23];
    const float* g3 = (const float*)d_in[24], *be3 = (const float*)d_in[25];

    char* ws = (char*)d_ws;
    size_t off = 0;
    auto alloc = [&](size_t n) { char* p = ws + off; off += (n + 255) & ~(size_t)255; return p; };
    unsigned short* w1aT = (unsigned short*)alloc((size_t)128 * 256 * 2);
    unsigned short* w1bT = (unsigned short*)alloc((size_t)256 * 256 * 2);
    unsigned short* w2aT = (unsigned short*)alloc((size_t)256 * 512 * 2);
    unsigned short* w2bT = (unsigned short*)alloc((size_t)512 * 512 * 2);
    unsigned short* w3aT = (unsigned short*)alloc((size_t)512 * 1024 * 2);
    unsigned short* w3bT = (unsigned short*)alloc((size_t)1024 * 1024 * 2);
    unsigned short* rp1T = (unsigned short*)alloc((size_t)128 * 256 * 2);
    unsigned short* rp2T = (unsigned short*)alloc((size_t)256 * 512 * 2);
    unsigned short* rp3T = (unsigned short*)alloc((size_t)512 * 1024 * 2);
    unsigned short* hA  = (unsigned short*)alloc((size_t)M_PAD * 512 * 2);
    unsigned short* hB  = (unsigned short*)alloc((size_t)M_PAD * 512 * 2);
    unsigned short* zin = (unsigned short*)alloc((size_t)M_PAD * 512 * 2);
    unsigned short* z1  = (unsigned short*)alloc((size_t)M_PAD * 1024 * 2);
    float* resb = (float*)alloc((size_t)M_PAD * 1024 * 4);
    int* deg     = (int*)alloc((size_t)NN * 4);
    int* row_ptr = (int*)alloc((size_t)NN * 4);
    int* cursor  = (int*)alloc((size_t)NN * 4);
    int* colv    = (int*)alloc((size_t)NE * 4);
    (void)ws_size; (void)in_sizes; (void)n_in; (void)out_size;

    // ---- CSR build (shared by all 3 blocks) ----
    zero_k<<<cdiv(NN, 256), 256, 0, stream>>>(deg, NN);
    hist_k<<<cdiv(NE, 256), 256, 0, stream>>>(ei, deg);
    scan_k<<<1, 1024, 0, stream>>>(deg, row_ptr, cursor);
    build_col_k<<<cdiv(NE, 256), 256, 0, stream>>>(ei, cursor, colv);

    // ---- weights -> bf16 transposed (N x K) ----
    wt_k<<<cdiv(128 * 256, 256), 256, 0, stream>>>(w1a, w1aT, 128, 256);
    wt_k<<<cdiv(256 * 256, 256), 256, 0, stream>>>(w1b, w1bT, 256, 256);
    wt_k<<<cdiv(256 * 512, 256), 256, 0, stream>>>(w2a, w2aT, 256, 512);
    wt_k<<<cdiv(512 * 512, 256), 256, 0, stream>>>(w2b, w2bT, 512, 512);
    wt_k<<<cdiv(512 * 1024, 256), 256, 0, stream>>>(w3a, w3aT, 512, 1024);
    wt_k<<<cdiv(1024 * 1024, 256), 256, 0, stream>>>(w3b, w3bT, 1024, 1024);
    wt_k<<<cdiv(128 * 256, 256), 256, 0, stream>>>(rp1, rp1T, 128, 256);
    wt_k<<<cdiv(256 * 512, 256), 256, 0, stream>>>(rp2, rp2T, 256, 512);
    wt_k<<<cdiv(512 * 1024, 256), 256, 0, stream>>>(rp3, rp3T, 512, 1024);

    // x -> bf16
    f32_to_bf16_k<<<cdiv((long)NN * 128 / 4, 256), 256, 0, stream>>>(x, hA, (long)NN * 128 / 4);

    // ---- block 1: Din=128, Dout=256, h = hA ----
    agg_gather_k<128><<<cdiv(NN, 4), 256, 0, stream>>>(hA, row_ptr, deg, colv, zin);
    gemm8_k<128, 0, 256, false><<<dim3(2, 196), 512, 0, stream>>>(
        zin, w1aT, b1a, nullptr, nullptr, nullptr, z1, nullptr, NN);
    gemm8_k<256, 128, 256, true><<<dim3(2, 196), 512, 0, stream>>>(
        z1, w1bT, b1b, hA, rp1T, rp1b, nullptr, resb, NN);
    ln_k<256, true><<<NN, 256, 0, stream>>>(resb, g1, be1, hB, nullptr);

    // ---- block 2: Din=256, Dout=512, h = hB ----
    agg_gather_k<256><<<cdiv(NN, 4), 256, 0, stream>>>(hB, row_ptr, deg, colv, zin);
    gemm8_k<256, 0, 512, false><<<dim3(4, 196), 512, 0, stream>>>(
        zin, w2aT, b2a, nullptr, nullptr, nullptr, z1, nullptr, NN);
    gemm8_k<512, 256, 512, true><<<dim3(4, 196), 512, 0, stream>>>(
        z1, w2bT, b2b, hB, rp2T, rp2b, nullptr, resb, NN);
    ln_k<512, true><<<NN, 256, 0, stream>>>(resb, g2, be2, hA, nullptr);

    // ---- block 3: Din=512, Dout=1024, h = hA ----
    agg_gather_k<512><<<cdiv(NN, 4), 256, 0, stream>>>(hA, row_ptr, deg, colv, zin);
    gemm8_k<512, 0, 1024, false><<<dim3(8, 196), 512, 0, stream>>>(
        zin, w3aT, b3a, nullptr, nullptr, nullptr, z1, nullptr, NN);
    gemm8_k<1024, 512, 1024, true><<<dim3(8, 196), 512, 0, stream>>>(
        z1, w3bT, b3b, hA, rp3T, rp3b, nullptr, resb, NN);
    ln_k<1024, false><<<NN, 256, 0, stream>>>(resb, g3, be3, nullptr, (float*)d_out);
}

// Round 3
// 1417.366 us; speedup vs baseline: 1.1757x; 1.1757x over previous
//
#include <hip/hip_runtime.h>
#include <stdint.h>

#define NN 50000
#define NE 800000
#define M_PAD 50048   // 391 * 128

typedef __attribute__((ext_vector_type(8))) short short8;
typedef __attribute__((ext_vector_type(4))) float f32x4;

static __device__ __forceinline__ float bf2f(unsigned short v) {
    union { unsigned u; float f; } c; c.u = ((unsigned)v) << 16; return c.f;
}
static __device__ __forceinline__ unsigned short f2bf(float f) {
    union { float f; unsigned u; } c; c.f = f;
    unsigned u = c.u;
    u += 0x7fffu + ((u >> 16) & 1u);   // RNE, inputs finite
    return (unsigned short)(u >> 16);
}

// ---------------- elementwise converters ----------------
__global__ void f32_to_bf16_k(const float* __restrict__ in, unsigned short* __restrict__ out, long n4) {
    long i = (long)blockIdx.x * 256 + threadIdx.x;
    if (i >= n4) return;
    float4 v = ((const float4*)in)[i];
    ushort4 o; o.x = f2bf(v.x); o.y = f2bf(v.y); o.z = f2bf(v.z); o.w = f2bf(v.w);
    ((ushort4*)out)[i] = o;
}
// W (K x N f32) -> Wt (N x K bf16). i = n*K + k (k fast => coalesced writes).
__global__ void wt_k(const float* __restrict__ w, unsigned short* __restrict__ wt, int K, int N) {
    int i = blockIdx.x * 256 + threadIdx.x;
    if (i >= K * N) return;
    int k = i % K, n = i / K;
    wt[i] = f2bf(w[(long)k * N + n]);
}

// ---------------- CSR build ----------------
__global__ void zero_k(int* __restrict__ p, int n) {
    int i = blockIdx.x * 256 + threadIdx.x;
    if (i < n) p[i] = 0;
}
__global__ void hist_k(const int* __restrict__ ei, int* __restrict__ deg) {
    int e = blockIdx.x * 256 + threadIdx.x;
    if (e >= NE) return;
    atomicAdd(&deg[ei[NE + e]], 1);
}
// single-block exclusive scan over deg[NN] -> row_ptr, cursor
__global__ __launch_bounds__(1024)
void scan_k(const int* __restrict__ deg, int* __restrict__ row_ptr, int* __restrict__ cursor) {
    constexpr int T = 1024, C = (NN + T - 1) / T;  // 49
    const int tid = threadIdx.x;
    const int base = tid * C;
    int s = 0;
#pragma unroll 4
    for (int i = 0; i < C; ++i) {
        int idx = base + i;
        if (idx < NN) s += deg[idx];
    }
    __shared__ int sm[T];
    sm[tid] = s;
    __syncthreads();
    for (int off = 1; off < T; off <<= 1) {
        int v = (tid >= off) ? sm[tid - off] : 0;
        __syncthreads();
        sm[tid] += v;
        __syncthreads();
    }
    int run = (tid == 0) ? 0 : sm[tid - 1];
#pragma unroll 4
    for (int i = 0; i < C; ++i) {
        int idx = base + i;
        if (idx < NN) {
            row_ptr[idx] = run;
            cursor[idx] = run;
            run += deg[idx];
        }
    }
}
__global__ void build_col_k(const int* __restrict__ ei, int* __restrict__ cursor, int* __restrict__ col) {
    int e = blockIdx.x * 256 + threadIdx.x;
    if (e >= NE) return;
    int d = ei[NE + e];
    int p = atomicAdd(&cursor[d], 1);
    col[p] = ei[e];
}

// ---------------- gather-aggregate: z[n] = h[n] + sum_{j->n} h[j], bf16 out ----------------
template <int V> struct VecT;
template <> struct VecT<2> { using T = unsigned int; };
template <> struct VecT<4> { using T = uint2; };
template <> struct VecT<8> { using T = uint4; };

template <int D>
__global__ __launch_bounds__(256)
void agg_gather_k(const unsigned short* __restrict__ h,
                  const int* __restrict__ row_ptr, const int* __restrict__ deg,
                  const int* __restrict__ col, unsigned short* __restrict__ z) {
    constexpr int V = D / 64;
    using VT = typename VecT<V>::T;
    union U { VT v; unsigned short s[V]; };
    const int node = blockIdx.x * 4 + (threadIdx.x >> 6);
    if (node >= NN) return;
    const int lane = threadIdx.x & 63;
    const size_t fb = (size_t)lane * V;

    float acc[V];
    {
        U b; b.v = *(const VT*)(h + (size_t)node * D + fb);
#pragma unroll
        for (int i = 0; i < V; ++i) acc[i] = bf2f(b.s[i]);
    }
    const int s = row_ptr[node];
    const int e = s + deg[node];
    int t = s;
    for (; t + 2 <= e; t += 2) {
        int s0 = col[t], s1 = col[t + 1];
        U a0, a1;
        a0.v = *(const VT*)(h + (size_t)s0 * D + fb);
        a1.v = *(const VT*)(h + (size_t)s1 * D + fb);
#pragma unroll
        for (int i = 0; i < V; ++i) acc[i] += bf2f(a0.s[i]);
#pragma unroll
        for (int i = 0; i < V; ++i) acc[i] += bf2f(a1.s[i]);
    }
    if (t < e) {
        U a; a.v = *(const VT*)(h + (size_t)col[t] * D + fb);
#pragma unroll
        for (int i = 0; i < V; ++i) acc[i] += bf2f(a.s[i]);
    }
    U o;
#pragma unroll
    for (int i = 0; i < V; ++i) o.s[i] = f2bf(acc[i]);
    *(VT*)(z + (size_t)node * D + fb) = o.v;
}

// ---------------- MFMA GEMM building blocks ----------------
// Stage a 128x64 bf16 tile (row stride = rstride shorts) into LDS via DMA.
// XOR swizzle folded into the per-lane SOURCE address: LDS slot s of row r
// holds k-block (s ^ (r&7)), matching the fragment-read addressing below.
static __device__ __forceinline__ void stage_tile128x64(
    const unsigned short* __restrict__ src, size_t rstride,
    unsigned short* lds, int wid, int lane) {
#pragma unroll
    for (int r = 0; r < 4; ++r) {
        const int rows8 = wid * 32 + r * 8;
        const int row = rows8 + (lane >> 3);
        const int kblk = (lane & 7) ^ (row & 7);
        __builtin_amdgcn_global_load_lds(
            (const __attribute__((address_space(1))) void*)(src + (size_t)row * rstride + (size_t)kblk * 8),
            (__attribute__((address_space(3))) void*)(lds + rows8 * 64),
            16, 0, 0);
    }
}

// XCD-aware bijective block swizzle (m204 formula), m-major logical order:
// each XCD gets a contiguous run of (m,n) tiles -> A panels fetched once per XCD L2.
#define GEMM_IDS(NT)                                                      \
    const int tid = threadIdx.x;                                          \
    const int lane = tid & 63;                                            \
    const int wid = tid >> 6;                                             \
    const int wm = wid & 1, wn = wid >> 1;                                \
    const int l15 = lane & 15, quad = lane >> 4;                          \
    int m0, n0;                                                           \
    {                                                                     \
        const int nwg = (int)(gridDim.x * gridDim.y);                     \
        const int orig = (int)(blockIdx.y * gridDim.x + blockIdx.x);      \
        const int q = nwg >> 3, r = nwg & 7;                              \
        const int xcd = orig & 7, idx = orig >> 3;                        \
        const int logical =                                               \
            (xcd < r ? xcd * (q + 1) : r * (q + 1) + (xcd - r) * q) + idx;\
        m0 = (logical / (NT)) * 128;                                      \
        n0 = (logical % (NT)) * 128;                                      \
    }

// Double-buffered 2-phase pipeline (catalog "minimum 2-phase"):
// issue next-tile global_load_lds BEFORE computing current tile; single
// counted drain (vmcnt(0)) + raw s_barrier AFTER the MFMAs -> staging
// latency overlaps ds_read+MFMA instead of being fully exposed.
// LDS = 2 x (8+8) KiB x2 = 64 KiB -> still 2 blocks/CU.
#define GEMM_PIPE(AP, BP, KS)                                                         \
    {                                                                                 \
        stage_tile128x64((AP) + (size_t)m0 * (KS), (KS), &lA[0][0], wid, lane);       \
        stage_tile128x64((BP) + (size_t)n0 * (KS), (KS), &lB[0][0], wid, lane);       \
        asm volatile("s_waitcnt vmcnt(0)" ::: "memory");                              \
        __builtin_amdgcn_s_barrier();                                                 \
        const int NT_ = (KS) / 64;                                                    \
        for (int t = 0; t < NT_; ++t) {                                               \
            const int cb = t & 1;                                                     \
            if (t + 1 < NT_) {                                                        \
                stage_tile128x64((AP) + (size_t)m0 * (KS) + (size_t)(t + 1) * 64,     \
                                 (KS), &lA[cb ^ 1][0], wid, lane);                    \
                stage_tile128x64((BP) + (size_t)n0 * (KS) + (size_t)(t + 1) * 64,     \
                                 (KS), &lB[cb ^ 1][0], wid, lane);                    \
            }                                                                         \
            _Pragma("unroll")                                                         \
            for (int kk = 0; kk < 2; ++kk) {                                          \
                short8 aF[4], bF[4];                                                  \
                _Pragma("unroll")                                                     \
                for (int i = 0; i < 4; ++i) {                                         \
                    int ml = wm * 64 + i * 16 + l15;                                  \
                    int kb = kk * 4 + quad;                                           \
                    aF[i] = *(const short8*)&lA[cb][(ml * 8 + (kb ^ (ml & 7))) * 8];  \
                    int nl = wn * 64 + i * 16 + l15;                                  \
                    bF[i] = *(const short8*)&lB[cb][(nl * 8 + (kb ^ (nl & 7))) * 8];  \
                }                                                                     \
                _Pragma("unroll")                                                     \
                for (int i = 0; i < 4; ++i)                                           \
                    _Pragma("unroll")                                                 \
                    for (int j = 0; j < 4; ++j)                                       \
                        acc[i][j] = __builtin_amdgcn_mfma_f32_16x16x32_bf16(          \
                            aF[i], bF[j], acc[i][j], 0, 0, 0);                        \
            }                                                                         \
            asm volatile("s_waitcnt vmcnt(0)" ::: "memory");                          \
            __builtin_amdgcn_s_barrier();                                             \
        }                                                                             \
    }

// C = bf16(relu(A(MxK) * Bt(NxK)^T + bias))  -- first MLP layer
template <int K, int N>
__global__ __launch_bounds__(256, 2)
void gemm_relu_k(const unsigned short* __restrict__ A, const unsigned short* __restrict__ Bt,
                 const float* __restrict__ bias, unsigned short* __restrict__ outH, int M) {
    __shared__ unsigned short lA[2][128 * 64];
    __shared__ unsigned short lB[2][128 * 64];
    GEMM_IDS(N / 128)
    f32x4 acc[4][4];
#pragma unroll
    for (int i = 0; i < 4; ++i)
#pragma unroll
        for (int j = 0; j < 4; ++j) acc[i][j] = (f32x4){0.f, 0.f, 0.f, 0.f};

    GEMM_PIPE(A, Bt, K)

#pragma unroll
    for (int i = 0; i < 4; ++i) {
#pragma unroll
        for (int j = 0; j < 4; ++j) {
            int col = n0 + wn * 64 + j * 16 + l15;
            float bv = bias[col];
#pragma unroll
            for (int r = 0; r < 4; ++r) {
                int row = m0 + wm * 64 + i * 16 + quad * 4 + r;
                if (row < M)
                    outH[(size_t)row * N + col] = f2bf(fmaxf(acc[i][j][r] + bv, 0.f));
            }
        }
    }
}

// out = relu( relu(A1*B1t^T + b1) + A2*B2t^T + b2 )  -- 2nd MLP layer + residual proj fused
// OUTBF16: write bf16 (consumed by bf16-input LN) instead of f32.
template <int K1, int K2, int N, bool OUTBF16>
__global__ __launch_bounds__(256, 2)
void gemm_fused_k(const unsigned short* __restrict__ A1, const unsigned short* __restrict__ B1t,
                  const float* __restrict__ b1,
                  const unsigned short* __restrict__ A2, const unsigned short* __restrict__ B2t,
                  const float* __restrict__ b2,
                  unsigned short* __restrict__ outH, float* __restrict__ outF, int M) {
    __shared__ unsigned short lA[2][128 * 64];
    __shared__ unsigned short lB[2][128 * 64];
    GEMM_IDS(N / 128)
    f32x4 acc[4][4];
#pragma unroll
    for (int i = 0; i < 4; ++i)
#pragma unroll
        for (int j = 0; j < 4; ++j) acc[i][j] = (f32x4){0.f, 0.f, 0.f, 0.f};

    // prefetch mid-bias so no vm load sits between the two pipes
    float bmid[4];
#pragma unroll
    for (int j = 0; j < 4; ++j) bmid[j] = b1[n0 + wn * 64 + j * 16 + l15];

    GEMM_PIPE(A1, B1t, K1)

    // in-register: acc = relu(acc + b1[col]); second pipe keeps accumulating additively
#pragma unroll
    for (int j = 0; j < 4; ++j) {
#pragma unroll
        for (int i = 0; i < 4; ++i)
#pragma unroll
            for (int r = 0; r < 4; ++r)
                acc[i][j][r] = fmaxf(acc[i][j][r] + bmid[j], 0.f);
    }

    GEMM_PIPE(A2, B2t, K2)

#pragma unroll
    for (int i = 0; i < 4; ++i) {
#pragma unroll
        for (int j = 0; j < 4; ++j) {
            int col = n0 + wn * 64 + j * 16 + l15;
            float bv = b2[col];
#pragma unroll
            for (int r = 0; r < 4; ++r) {
                int row = m0 + wm * 64 + i * 16 + quad * 4 + r;
                if (row < M) {
                    float v = fmaxf(acc[i][j][r] + bv, 0.f);
                    if constexpr (OUTBF16) outH[(size_t)row * N + col] = f2bf(v);
                    else                   outF[(size_t)row * N + col] = v;
                }
            }
        }
    }
}

// ---------------- LayerNorm: one block per row ----------------
template <int D, bool INBF16, bool BF16OUT>
__global__ __launch_bounds__(256)
void ln_k(const unsigned short* __restrict__ tH, const float* __restrict__ tF,
          const float* __restrict__ g, const float* __restrict__ b,
          unsigned short* __restrict__ outH, float* __restrict__ outF) {
    constexpr int VPT = D / 256;
    const int row = blockIdx.x;
    const int tid = threadIdx.x;
    float vals[VPT];
    float s = 0.f, ss = 0.f;
#pragma unroll
    for (int i = 0; i < VPT; ++i) {
        int c = i * 256 + tid;
        float v = INBF16 ? bf2f(tH[(size_t)row * D + c]) : tF[(size_t)row * D + c];
        vals[i] = v; s += v; ss += v * v;
    }
#pragma unroll
    for (int off = 32; off; off >>= 1) { s += __shfl_down(s, off); ss += __shfl_down(ss, off); }
    __shared__ float ps[4], pss[4];
    int lane = tid & 63, wv = tid >> 6;
    if (lane == 0) { ps[wv] = s; pss[wv] = ss; }
    __syncthreads();
    float st = ps[0] + ps[1] + ps[2] + ps[3];
    float sst = pss[0] + pss[1] + pss[2] + pss[3];
    float mean = st / D;
    float var = sst / D - mean * mean;
    float inv = rsqrtf(var + 1e-5f);
#pragma unroll
    for (int i = 0; i < VPT; ++i) {
        int c = i * 256 + tid;
        float o = (vals[i] - mean) * inv * g[c] + b[c];
        if (BF16OUT) outH[(size_t)row * D + c] = f2bf(o);
        else outF[(size_t)row * D + c] = o;
    }
}

static inline int cdiv(long a, long b) { return (int)((a + b - 1) / b); }

extern "C" void kernel_launch(void* const* d_in, const int* in_sizes, int n_in,
                              void* d_out, int out_size, void* d_ws, size_t ws_size,
                              hipStream_t stream) {
    const float* x   = (const float*)d_in[0];
    const int*   ei  = (const int*)  d_in[1];
    const float* w1a = (const float*)d_in[2],  *b1a = (const float*)d_in[3];
    const float* w1b = (const float*)d_in[4],  *b1b = (const float*)d_in[5];
    const float* w2a = (const float*)d_in[6],  *b2a = (const float*)d_in[7];
    const float* w2b = (const float*)d_in[8],  *b2b = (const float*)d_in[9];
    const float* w3a = (const float*)d_in[10], *b3a = (const float*)d_in[11];
    const float* w3b = (const float*)d_in[12], *b3b = (const float*)d_in[13];
    const float* rp1 = (const float*)d_in[14], *rp1b = (const float*)d_in[15];
    const float* rp2 = (const float*)d_in[16], *rp2b = (const float*)d_in[17];
    const float* rp3 = (const float*)d_in[18], *rp3b = (const float*)d_in[19];
    const float* g1 = (const float*)d_in[20], *be1 = (const float*)d_in[21];
    const float* g2 = (const float*)d_in[22], *be2 = (const float*)d_in[23];
    const float* g3 = (const float*)d_in[24], *be3 = (const float*)d_in[25];

    char* ws = (char*)d_ws;
    size_t off = 0;
    auto alloc = [&](size_t n) { char* p = ws + off; off += (n + 255) & ~(size_t)255; return p; };
    unsigned short* w1aT = (unsigned short*)alloc((size_t)128 * 256 * 2);
    unsigned short* w1bT = (unsigned short*)alloc((size_t)256 * 256 * 2);
    unsigned short* w2aT = (unsigned short*)alloc((size_t)256 * 512 * 2);
    unsigned short* w2bT = (unsigned short*)alloc((size_t)512 * 512 * 2);
    unsigned short* w3aT = (unsigned short*)alloc((size_t)512 * 1024 * 2);
    unsigned short* w3bT = (unsigned short*)alloc((size_t)1024 * 1024 * 2);
    unsigned short* rp1T = (unsigned short*)alloc((size_t)128 * 256 * 2);
    unsigned short* rp2T = (unsigned short*)alloc((size_t)256 * 512 * 2);
    unsigned short* rp3T = (unsigned short*)alloc((size_t)512 * 1024 * 2);
    unsigned short* hA  = (unsigned short*)alloc((size_t)M_PAD * 512 * 2);
    unsigned short* hB  = (unsigned short*)alloc((size_t)M_PAD * 512 * 2);
    unsigned short* zin = (unsigned short*)alloc((size_t)M_PAD * 512 * 2);
    unsigned short* z1  = (unsigned short*)alloc((size_t)M_PAD * 1024 * 2);
    float* resb = (float*)alloc((size_t)M_PAD * 1024 * 4);
    int* deg     = (int*)alloc((size_t)NN * 4);
    int* row_ptr = (int*)alloc((size_t)NN * 4);
    int* cursor  = (int*)alloc((size_t)NN * 4);
    int* colv    = (int*)alloc((size_t)NE * 4);
    (void)ws_size; (void)in_sizes; (void)n_in; (void)out_size;

    // ---- CSR build (shared by all 3 blocks) ----
    zero_k<<<cdiv(NN, 256), 256, 0, stream>>>(deg, NN);
    hist_k<<<cdiv(NE, 256), 256, 0, stream>>>(ei, deg);
    scan_k<<<1, 1024, 0, stream>>>(deg, row_ptr, cursor);
    build_col_k<<<cdiv(NE, 256), 256, 0, stream>>>(ei, cursor, colv);

    // ---- weights -> bf16 transposed (N x K) ----
    wt_k<<<cdiv(128 * 256, 256), 256, 0, stream>>>(w1a, w1aT, 128, 256);
    wt_k<<<cdiv(256 * 256, 256), 256, 0, stream>>>(w1b, w1bT, 256, 256);
    wt_k<<<cdiv(256 * 512, 256), 256, 0, stream>>>(w2a, w2aT, 256, 512);
    wt_k<<<cdiv(512 * 512, 256), 256, 0, stream>>>(w2b, w2bT, 512, 512);
    wt_k<<<cdiv(512 * 1024, 256), 256, 0, stream>>>(w3a, w3aT, 512, 1024);
    wt_k<<<cdiv(1024 * 1024, 256), 256, 0, stream>>>(w3b, w3bT, 1024, 1024);
    wt_k<<<cdiv(128 * 256, 256), 256, 0, stream>>>(rp1, rp1T, 128, 256);
    wt_k<<<cdiv(256 * 512, 256), 256, 0, stream>>>(rp2, rp2T, 256, 512);
    wt_k<<<cdiv(512 * 1024, 256), 256, 0, stream>>>(rp3, rp3T, 512, 1024);

    // x -> bf16
    f32_to_bf16_k<<<cdiv((long)NN * 128 / 4, 256), 256, 0, stream>>>(x, hA, (long)NN * 128 / 4);

    // ---- block 1: Din=128, Dout=256, h = hA ----
    agg_gather_k<128><<<cdiv(NN, 4), 256, 0, stream>>>(hA, row_ptr, deg, colv, zin);
    gemm_relu_k<128, 256><<<dim3(2, 391), 256, 0, stream>>>(zin, w1aT, b1a, z1, NN);
    // fused out -> bf16, reuse zin (gemm_relu consumed it)
    gemm_fused_k<256, 128, 256, true><<<dim3(2, 391), 256, 0, stream>>>(
        z1, w1bT, b1b, hA, rp1T, rp1b, zin, nullptr, NN);
    ln_k<256, true, true><<<NN, 256, 0, stream>>>(zin, nullptr, g1, be1, hB, nullptr);

    // ---- block 2: Din=256, Dout=512, h = hB ----
    agg_gather_k<256><<<cdiv(NN, 4), 256, 0, stream>>>(hB, row_ptr, deg, colv, zin);
    gemm_relu_k<256, 512><<<dim3(4, 391), 256, 0, stream>>>(zin, w2aT, b2a, z1, NN);
    gemm_fused_k<512, 256, 512, true><<<dim3(4, 391), 256, 0, stream>>>(
        z1, w2bT, b2b, hB, rp2T, rp2b, zin, nullptr, NN);
    ln_k<512, true, true><<<NN, 256, 0, stream>>>(zin, nullptr, g2, be2, hA, nullptr);

    // ---- block 3: Din=512, Dout=1024, h = hA ----
    agg_gather_k<512><<<cdiv(NN, 4), 256, 0, stream>>>(hA, row_ptr, deg, colv, zin);
    gemm_relu_k<512, 1024><<<dim3(8, 391), 256, 0, stream>>>(zin, w3aT, b3a, z1, NN);
    gemm_fused_k<1024, 512, 1024, false><<<dim3(8, 391), 256, 0, stream>>>(
        z1, w3bT, b3b, hA, rp3T, rp3b, nullptr, resb, NN);
    ln_k<1024, false, false><<<NN, 256, 0, stream>>>(nullptr, resb, g3, be3, nullptr, (float*)d_out);
}

// Round 4
// 1267.706 us; speedup vs baseline: 1.3144x; 1.1181x over previous
//
#include <hip/hip_runtime.h>
#include <stdint.h>

#define NN 50000
#define NE 800000
#define M_PAD 50048   // 391 * 128

typedef __attribute__((ext_vector_type(8))) short short8;
typedef __attribute__((ext_vector_type(4))) float f32x4;

static __device__ __forceinline__ float bf2f(unsigned short v) {
    union { unsigned u; float f; } c; c.u = ((unsigned)v) << 16; return c.f;
}
static __device__ __forceinline__ unsigned short f2bf(float f) {
    union { float f; unsigned u; } c; c.f = f;
    unsigned u = c.u;
    u += 0x7fffu + ((u >> 16) & 1u);   // RNE, inputs finite
    return (unsigned short)(u >> 16);
}

// ---------------- elementwise converters ----------------
__global__ void f32_to_bf16_k(const float* __restrict__ in, unsigned short* __restrict__ out, long n4) {
    long i = (long)blockIdx.x * 256 + threadIdx.x;
    if (i >= n4) return;
    float4 v = ((const float4*)in)[i];
    ushort4 o; o.x = f2bf(v.x); o.y = f2bf(v.y); o.z = f2bf(v.z); o.w = f2bf(v.w);
    ((ushort4*)out)[i] = o;
}
// W (K x N f32) -> Wt (N x K bf16), LDS-tiled transpose: both sides coalesced.
// Grid: dim3(N/32, K/32), 256 threads (32x8). K,N are multiples of 32.
__global__ __launch_bounds__(256)
void wt_k(const float* __restrict__ w, unsigned short* __restrict__ wt, int K, int N) {
    __shared__ unsigned short t[32][33];
    const int bk = blockIdx.y * 32, bn = blockIdx.x * 32;
    const int tx = threadIdx.x & 31, ty = threadIdx.x >> 5;
#pragma unroll
    for (int r = 0; r < 32; r += 8)
        t[ty + r][tx] = f2bf(w[(size_t)(bk + ty + r) * N + bn + tx]);
    __syncthreads();
#pragma unroll
    for (int r = 0; r < 32; r += 8)
        wt[(size_t)(bn + ty + r) * K + bk + tx] = t[tx][ty + r];
}

// ---------------- CSR build ----------------
__global__ void zero_k(int* __restrict__ p, int n) {
    int i = blockIdx.x * 256 + threadIdx.x;
    if (i < n) p[i] = 0;
}
__global__ void hist_k(const int* __restrict__ ei, int* __restrict__ deg) {
    int e = blockIdx.x * 256 + threadIdx.x;
    if (e >= NE) return;
    atomicAdd(&deg[ei[NE + e]], 1);
}
// single-block exclusive scan over deg[NN] -> row_ptr, cursor
__global__ __launch_bounds__(1024)
void scan_k(const int* __restrict__ deg, int* __restrict__ row_ptr, int* __restrict__ cursor) {
    constexpr int T = 1024, C = (NN + T - 1) / T;  // 49
    const int tid = threadIdx.x;
    const int base = tid * C;
    int s = 0;
#pragma unroll 4
    for (int i = 0; i < C; ++i) {
        int idx = base + i;
        if (idx < NN) s += deg[idx];
    }
    __shared__ int sm[T];
    sm[tid] = s;
    __syncthreads();
    for (int off = 1; off < T; off <<= 1) {
        int v = (tid >= off) ? sm[tid - off] : 0;
        __syncthreads();
        sm[tid] += v;
        __syncthreads();
    }
    int run = (tid == 0) ? 0 : sm[tid - 1];
#pragma unroll 4
    for (int i = 0; i < C; ++i) {
        int idx = base + i;
        if (idx < NN) {
            row_ptr[idx] = run;
            cursor[idx] = run;
            run += deg[idx];
        }
    }
}
__global__ void build_col_k(const int* __restrict__ ei, int* __restrict__ cursor, int* __restrict__ col) {
    int e = blockIdx.x * 256 + threadIdx.x;
    if (e >= NE) return;
    int d = ei[NE + e];
    int p = atomicAdd(&cursor[d], 1);
    col[p] = ei[e];
}

// ---------------- gather-aggregate: z[n] = h[n] + sum_{j->n} h[j], bf16 out ----------------
template <int V> struct VecT;
template <> struct VecT<2> { using T = unsigned int; };
template <> struct VecT<4> { using T = uint2; };
template <> struct VecT<8> { using T = uint4; };

template <int D>
__global__ __launch_bounds__(256)
void agg_gather_k(const unsigned short* __restrict__ h,
                  const int* __restrict__ row_ptr, const int* __restrict__ deg,
                  const int* __restrict__ col, unsigned short* __restrict__ z) {
    constexpr int V = D / 64;
    using VT = typename VecT<V>::T;
    union U { VT v; unsigned short s[V]; };
    const int node = blockIdx.x * 4 + (threadIdx.x >> 6);
    if (node >= NN) return;
    const int lane = threadIdx.x & 63;
    const size_t fb = (size_t)lane * V;

    float acc[V];
    {
        U b; b.v = *(const VT*)(h + (size_t)node * D + fb);
#pragma unroll
        for (int i = 0; i < V; ++i) acc[i] = bf2f(b.s[i]);
    }
    const int s = row_ptr[node];
    const int e = s + deg[node];
    int t = s;
    for (; t + 2 <= e; t += 2) {
        int s0 = col[t], s1 = col[t + 1];
        U a0, a1;
        a0.v = *(const VT*)(h + (size_t)s0 * D + fb);
        a1.v = *(const VT*)(h + (size_t)s1 * D + fb);
#pragma unroll
        for (int i = 0; i < V; ++i) acc[i] += bf2f(a0.s[i]);
#pragma unroll
        for (int i = 0; i < V; ++i) acc[i] += bf2f(a1.s[i]);
    }
    if (t < e) {
        U a; a.v = *(const VT*)(h + (size_t)col[t] * D + fb);
#pragma unroll
        for (int i = 0; i < V; ++i) acc[i] += bf2f(a.s[i]);
    }
    U o;
#pragma unroll
    for (int i = 0; i < V; ++i) o.s[i] = f2bf(acc[i]);
    *(VT*)(z + (size_t)node * D + fb) = o.v;
}

// ---------------- MFMA GEMM building blocks (R1 structure: single-buffered) ----------------
// Stage a 128x64 bf16 tile (row stride = rstride shorts) into LDS via DMA.
// XOR swizzle folded into the per-lane SOURCE address: LDS slot s of row r
// holds k-block (s ^ (r&7)), matching the fragment-read addressing below.
static __device__ __forceinline__ void stage_tile128x64(
    const unsigned short* __restrict__ src, size_t rstride,
    unsigned short* lds, int wid, int lane) {
#pragma unroll
    for (int r = 0; r < 4; ++r) {
        const int rows8 = wid * 32 + r * 8;
        const int row = rows8 + (lane >> 3);
        const int kblk = (lane & 7) ^ (row & 7);
        __builtin_amdgcn_global_load_lds(
            (const __attribute__((address_space(1))) void*)(src + (size_t)row * rstride + (size_t)kblk * 8),
            (__attribute__((address_space(3))) void*)(lds + rows8 * 64),
            16, 0, 0);
    }
}

// XCD-aware bijective block swizzle (m204 formula), m-major logical order:
// each XCD gets a contiguous run of (m,n) tiles -> A panels fetched once per XCD L2.
#define GEMM_IDS(NT)                                                      \
    const int tid = threadIdx.x;                                          \
    const int lane = tid & 63;                                            \
    const int wid = tid >> 6;                                             \
    const int wm = wid & 1, wn = wid >> 1;                                \
    const int l15 = lane & 15, quad = lane >> 4;                          \
    int m0, n0;                                                           \
    {                                                                     \
        const int nwg = (int)(gridDim.x * gridDim.y);                     \
        const int orig = (int)(blockIdx.y * gridDim.x + blockIdx.x);      \
        const int q = nwg >> 3, r = nwg & 7;                              \
        const int xcd = orig & 7, idx = orig >> 3;                        \
        const int logical =                                               \
            (xcd < r ? xcd * (q + 1) : r * (q + 1) + (xcd - r) * q) + idx;\
        m0 = (logical / (NT)) * 128;                                      \
        n0 = (logical % (NT)) * 128;                                      \
    }

// R1 K-loop: stage -> syncthreads (drain) -> compute -> syncthreads.
// 32 KiB LDS -> ~3 blocks/CU; inter-block wave overlap hides staging (m114).
#define GEMM_KSTEP(AP, BP, KS)                                                        \
    for (int k0 = 0; k0 < (KS); k0 += 64) {                                           \
        stage_tile128x64((AP) + (size_t)m0 * (KS) + k0, (KS), lA, wid, lane);         \
        stage_tile128x64((BP) + (size_t)n0 * (KS) + k0, (KS), lB, wid, lane);         \
        __syncthreads();                                                              \
        _Pragma("unroll")                                                             \
        for (int kk = 0; kk < 2; ++kk) {                                              \
            short8 aF[4], bF[4];                                                      \
            _Pragma("unroll")                                                         \
            for (int i = 0; i < 4; ++i) {                                             \
                int ml = wm * 64 + i * 16 + l15;                                      \
                int kb = kk * 4 + quad;                                               \
                aF[i] = *(const short8*)&lA[(ml * 8 + (kb ^ (ml & 7))) * 8];          \
                int nl = wn * 64 + i * 16 + l15;                                      \
                bF[i] = *(const short8*)&lB[(nl * 8 + (kb ^ (nl & 7))) * 8];          \
            }                                                                         \
            _Pragma("unroll")                                                         \
            for (int i = 0; i < 4; ++i)                                               \
                _Pragma("unroll")                                                     \
                for (int j = 0; j < 4; ++j)                                           \
                    acc[i][j] = __builtin_amdgcn_mfma_f32_16x16x32_bf16(              \
                        aF[i], bF[j], acc[i][j], 0, 0, 0);                            \
        }                                                                             \
        __syncthreads();                                                              \
    }

// C = bf16(relu(A(MxK) * Bt(NxK)^T + bias))  -- first MLP layer
template <int K, int N>
__global__ __launch_bounds__(256, 2)
void gemm_relu_k(const unsigned short* __restrict__ A, const unsigned short* __restrict__ Bt,
                 const float* __restrict__ bias, unsigned short* __restrict__ outH, int M) {
    __shared__ unsigned short lA[128 * 64];
    __shared__ unsigned short lB[128 * 64];
    GEMM_IDS(N / 128)
    f32x4 acc[4][4];
#pragma unroll
    for (int i = 0; i < 4; ++i)
#pragma unroll
        for (int j = 0; j < 4; ++j) acc[i][j] = (f32x4){0.f, 0.f, 0.f, 0.f};

    GEMM_KSTEP(A, Bt, K)

#pragma unroll
    for (int i = 0; i < 4; ++i) {
#pragma unroll
        for (int j = 0; j < 4; ++j) {
            int col = n0 + wn * 64 + j * 16 + l15;
            float bv = bias[col];
#pragma unroll
            for (int r = 0; r < 4; ++r) {
                int row = m0 + wm * 64 + i * 16 + quad * 4 + r;
                if (row < M)
                    outH[(size_t)row * N + col] = f2bf(fmaxf(acc[i][j][r] + bv, 0.f));
            }
        }
    }
}

// out = relu( relu(A1*B1t^T + b1) + A2*B2t^T + b2 )  -- 2nd MLP layer + residual proj fused
// OUTBF16: write bf16 (consumed by bf16-input LN) instead of f32.
template <int K1, int K2, int N, bool OUTBF16>
__global__ __launch_bounds__(256, 2)
void gemm_fused_k(const unsigned short* __restrict__ A1, const unsigned short* __restrict__ B1t,
                  const float* __restrict__ b1,
                  const unsigned short* __restrict__ A2, const unsigned short* __restrict__ B2t,
                  const float* __restrict__ b2,
                  unsigned short* __restrict__ outH, float* __restrict__ outF, int M) {
    __shared__ unsigned short lA[128 * 64];
    __shared__ unsigned short lB[128 * 64];
    GEMM_IDS(N / 128)
    f32x4 acc[4][4];
#pragma unroll
    for (int i = 0; i < 4; ++i)
#pragma unroll
        for (int j = 0; j < 4; ++j) acc[i][j] = (f32x4){0.f, 0.f, 0.f, 0.f};

    // prefetch mid-bias; drained by first __syncthreads anyway
    float bmid[4];
#pragma unroll
    for (int j = 0; j < 4; ++j) bmid[j] = b1[n0 + wn * 64 + j * 16 + l15];

    GEMM_KSTEP(A1, B1t, K1)

    // in-register: acc = relu(acc + b1[col]); second pipe keeps accumulating additively
#pragma unroll
    for (int j = 0; j < 4; ++j) {
#pragma unroll
        for (int i = 0; i < 4; ++i)
#pragma unroll
            for (int r = 0; r < 4; ++r)
                acc[i][j][r] = fmaxf(acc[i][j][r] + bmid[j], 0.f);
    }

    GEMM_KSTEP(A2, B2t, K2)

#pragma unroll
    for (int i = 0; i < 4; ++i) {
#pragma unroll
        for (int j = 0; j < 4; ++j) {
            int col = n0 + wn * 64 + j * 16 + l15;
            float bv = b2[col];
#pragma unroll
            for (int r = 0; r < 4; ++r) {
                int row = m0 + wm * 64 + i * 16 + quad * 4 + r;
                if (row < M) {
                    float v = fmaxf(acc[i][j][r] + bv, 0.f);
                    if constexpr (OUTBF16) outH[(size_t)row * N + col] = f2bf(v);
                    else                   outF[(size_t)row * N + col] = v;
                }
            }
        }
    }
}

// ---------------- LayerNorm: one block per row, vectorized contiguous loads ----------------
template <int D, bool INBF16, bool BF16OUT>
__global__ __launch_bounds__(256)
void ln_k(const unsigned short* __restrict__ tH, const float* __restrict__ tF,
          const float* __restrict__ g, const float* __restrict__ b,
          unsigned short* __restrict__ outH, float* __restrict__ outF) {
    constexpr int VPT = D / 256;
    const int row = blockIdx.x;
    const int tid = threadIdx.x;
    const int c0 = tid * VPT;
    float vals[VPT];
    // vectorized load of VPT contiguous elements
    if constexpr (INBF16) {
        const unsigned short* p = tH + (size_t)row * D + c0;
        if constexpr (VPT == 1) { vals[0] = bf2f(p[0]); }
        else if constexpr (VPT == 2) {
            ushort2 u = *(const ushort2*)p; vals[0] = bf2f(u.x); vals[1] = bf2f(u.y);
        } else {
            ushort4 u = *(const ushort4*)p;
            vals[0] = bf2f(u.x); vals[1] = bf2f(u.y); vals[2] = bf2f(u.z); vals[3] = bf2f(u.w);
        }
    } else {
        const float* p = tF + (size_t)row * D + c0;
        if constexpr (VPT == 1) { vals[0] = p[0]; }
        else if constexpr (VPT == 2) { float2 u = *(const float2*)p; vals[0] = u.x; vals[1] = u.y; }
        else { float4 u = *(const float4*)p; vals[0] = u.x; vals[1] = u.y; vals[2] = u.z; vals[3] = u.w; }
    }
    float s = 0.f, ss = 0.f;
#pragma unroll
    for (int i = 0; i < VPT; ++i) { s += vals[i]; ss += vals[i] * vals[i]; }
#pragma unroll
    for (int off = 32; off; off >>= 1) { s += __shfl_down(s, off); ss += __shfl_down(ss, off); }
    __shared__ float ps[4], pss[4];
    int lane = tid & 63, wv = tid >> 6;
    if (lane == 0) { ps[wv] = s; pss[wv] = ss; }
    __syncthreads();
    float st = ps[0] + ps[1] + ps[2] + ps[3];
    float sst = pss[0] + pss[1] + pss[2] + pss[3];
    float mean = st / D;
    float var = sst / D - mean * mean;
    float inv = rsqrtf(var + 1e-5f);
    float outv[VPT];
#pragma unroll
    for (int i = 0; i < VPT; ++i)
        outv[i] = (vals[i] - mean) * inv * g[c0 + i] + b[c0 + i];
    if constexpr (BF16OUT) {
        unsigned short* p = outH + (size_t)row * D + c0;
        if constexpr (VPT == 1) { p[0] = f2bf(outv[0]); }
        else if constexpr (VPT == 2) {
            ushort2 u; u.x = f2bf(outv[0]); u.y = f2bf(outv[1]); *(ushort2*)p = u;
        } else {
            ushort4 u; u.x = f2bf(outv[0]); u.y = f2bf(outv[1]); u.z = f2bf(outv[2]); u.w = f2bf(outv[3]);
            *(ushort4*)p = u;
        }
    } else {
        float* p = outF + (size_t)row * D + c0;
        if constexpr (VPT == 1) { p[0] = outv[0]; }
        else if constexpr (VPT == 2) { float2 u; u.x = outv[0]; u.y = outv[1]; *(float2*)p = u; }
        else { float4 u; u.x = outv[0]; u.y = outv[1]; u.z = outv[2]; u.w = outv[3]; *(float4*)p = u; }
    }
}

static inline int cdiv(long a, long b) { return (int)((a + b - 1) / b); }

extern "C" void kernel_launch(void* const* d_in, const int* in_sizes, int n_in,
                              void* d_out, int out_size, void* d_ws, size_t ws_size,
                              hipStream_t stream) {
    const float* x   = (const float*)d_in[0];
    const int*   ei  = (const int*)  d_in[1];
    const float* w1a = (const float*)d_in[2],  *b1a = (const float*)d_in[3];
    const float* w1b = (const float*)d_in[4],  *b1b = (const float*)d_in[5];
    const float* w2a = (const float*)d_in[6],  *b2a = (const float*)d_in[7];
    const float* w2b = (const float*)d_in[8],  *b2b = (const float*)d_in[9];
    const float* w3a = (const float*)d_in[10], *b3a = (const float*)d_in[11];
    const float* w3b = (const float*)d_in[12], *b3b = (const float*)d_in[13];
    const float* rp1 = (const float*)d_in[14], *rp1b = (const float*)d_in[15];
    const float* rp2 = (const float*)d_in[16], *rp2b = (const float*)d_in[17];
    const float* rp3 = (const float*)d_in[18], *rp3b = (const float*)d_in[19];
    const float* g1 = (const float*)d_in[20], *be1 = (const float*)d_in[21];
    const float* g2 = (const float*)d_in[22], *be2 = (const float*)d_in[23];
    const float* g3 = (const float*)d_in[24], *be3 = (const float*)d_in[25];

    char* ws = (char*)d_ws;
    size_t off = 0;
    auto alloc = [&](size_t n) { char* p = ws + off; off += (n + 255) & ~(size_t)255; return p; };
    unsigned short* w1aT = (unsigned short*)alloc((size_t)128 * 256 * 2);
    unsigned short* w1bT = (unsigned short*)alloc((size_t)256 * 256 * 2);
    unsigned short* w2aT = (unsigned short*)alloc((size_t)256 * 512 * 2);
    unsigned short* w2bT = (unsigned short*)alloc((size_t)512 * 512 * 2);
    unsigned short* w3aT = (unsigned short*)alloc((size_t)512 * 1024 * 2);
    unsigned short* w3bT = (unsigned short*)alloc((size_t)1024 * 1024 * 2);
    unsigned short* rp1T = (unsigned short*)alloc((size_t)128 * 256 * 2);
    unsigned short* rp2T = (unsigned short*)alloc((size_t)256 * 512 * 2);
    unsigned short* rp3T = (unsigned short*)alloc((size_t)512 * 1024 * 2);
    unsigned short* hA  = (unsigned short*)alloc((size_t)M_PAD * 512 * 2);
    unsigned short* hB  = (unsigned short*)alloc((size_t)M_PAD * 512 * 2);
    unsigned short* zin = (unsigned short*)alloc((size_t)M_PAD * 512 * 2);
    unsigned short* z1  = (unsigned short*)alloc((size_t)M_PAD * 1024 * 2);
    float* resb = (float*)alloc((size_t)M_PAD * 1024 * 4);
    int* deg     = (int*)alloc((size_t)NN * 4);
    int* row_ptr = (int*)alloc((size_t)NN * 4);
    int* cursor  = (int*)alloc((size_t)NN * 4);
    int* colv    = (int*)alloc((size_t)NE * 4);
    (void)ws_size; (void)in_sizes; (void)n_in; (void)out_size;

    // ---- CSR build (shared by all 3 blocks) ----
    zero_k<<<cdiv(NN, 256), 256, 0, stream>>>(deg, NN);
    hist_k<<<cdiv(NE, 256), 256, 0, stream>>>(ei, deg);
    scan_k<<<1, 1024, 0, stream>>>(deg, row_ptr, cursor);
    build_col_k<<<cdiv(NE, 256), 256, 0, stream>>>(ei, cursor, colv);

    // ---- weights -> bf16 transposed (N x K), LDS-tiled ----
    wt_k<<<dim3(256 / 32, 128 / 32), 256, 0, stream>>>(w1a, w1aT, 128, 256);
    wt_k<<<dim3(256 / 32, 256 / 32), 256, 0, stream>>>(w1b, w1bT, 256, 256);
    wt_k<<<dim3(512 / 32, 256 / 32), 256, 0, stream>>>(w2a, w2aT, 256, 512);
    wt_k<<<dim3(512 / 32, 512 / 32), 256, 0, stream>>>(w2b, w2bT, 512, 512);
    wt_k<<<dim3(1024 / 32, 512 / 32), 256, 0, stream>>>(w3a, w3aT, 512, 1024);
    wt_k<<<dim3(1024 / 32, 1024 / 32), 256, 0, stream>>>(w3b, w3bT, 1024, 1024);
    wt_k<<<dim3(256 / 32, 128 / 32), 256, 0, stream>>>(rp1, rp1T, 128, 256);
    wt_k<<<dim3(512 / 32, 256 / 32), 256, 0, stream>>>(rp2, rp2T, 256, 512);
    wt_k<<<dim3(1024 / 32, 512 / 32), 256, 0, stream>>>(rp3, rp3T, 512, 1024);

    // x -> bf16
    f32_to_bf16_k<<<cdiv((long)NN * 128 / 4, 256), 256, 0, stream>>>(x, hA, (long)NN * 128 / 4);

    // ---- block 1: Din=128, Dout=256, h = hA ----
    agg_gather_k<128><<<cdiv(NN, 4), 256, 0, stream>>>(hA, row_ptr, deg, colv, zin);
    gemm_relu_k<128, 256><<<dim3(2, 391), 256, 0, stream>>>(zin, w1aT, b1a, z1, NN);
    // fused out -> bf16, reuse zin (gemm_relu consumed it)
    gemm_fused_k<256, 128, 256, true><<<dim3(2, 391), 256, 0, stream>>>(
        z1, w1bT, b1b, hA, rp1T, rp1b, zin, nullptr, NN);
    ln_k<256, true, true><<<NN, 256, 0, stream>>>(zin, nullptr, g1, be1, hB, nullptr);

    // ---- block 2: Din=256, Dout=512, h = hB ----
    agg_gather_k<256><<<cdiv(NN, 4), 256, 0, stream>>>(hB, row_ptr, deg, colv, zin);
    gemm_relu_k<256, 512><<<dim3(4, 391), 256, 0, stream>>>(zin, w2aT, b2a, z1, NN);
    gemm_fused_k<512, 256, 512, true><<<dim3(4, 391), 256, 0, stream>>>(
        z1, w2bT, b2b, hB, rp2T, rp2b, zin, nullptr, NN);
    ln_k<512, true, true><<<NN, 256, 0, stream>>>(zin, nullptr, g2, be2, hA, nullptr);

    // ---- block 3: Din=512, Dout=1024, h = hA ----
    agg_gather_k<512><<<cdiv(NN, 4), 256, 0, stream>>>(hA, row_ptr, deg, colv, zin);
    gemm_relu_k<512, 1024><<<dim3(8, 391), 256, 0, stream>>>(zin, w3aT, b3a, z1, NN);
    gemm_fused_k<1024, 512, 1024, false><<<dim3(8, 391), 256, 0, stream>>>(
        z1, w3bT, b3b, hA, rp3T, rp3b, nullptr, resb, NN);
    ln_k<1024, false, false><<<NN, 256, 0, stream>>>(nullptr, resb, g3, be3, nullptr, (float*)d_out);
}

// Round 5
// 1183.790 us; speedup vs baseline: 1.4076x; 1.0709x over previous
//
#include <hip/hip_runtime.h>
#include <stdint.h>

#define NN 50000
#define NE 800000
#define M_PAD 50048   // 391 * 128

typedef __attribute__((ext_vector_type(8))) short short8;
typedef __attribute__((ext_vector_type(4))) float f32x4;

static __device__ __forceinline__ float bf2f(unsigned short v) {
    union { unsigned u; float f; } c; c.u = ((unsigned)v) << 16; return c.f;
}
static __device__ __forceinline__ unsigned short f2bf(float f) {
    union { float f; unsigned u; } c; c.f = f;
    unsigned u = c.u;
    u += 0x7fffu + ((u >> 16) & 1u);   // RNE, inputs finite
    return (unsigned short)(u >> 16);
}

// ---------------- elementwise converters ----------------
__global__ void f32_to_bf16_k(const float* __restrict__ in, unsigned short* __restrict__ out, long n4) {
    long i = (long)blockIdx.x * 256 + threadIdx.x;
    if (i >= n4) return;
    float4 v = ((const float4*)in)[i];
    ushort4 o; o.x = f2bf(v.x); o.y = f2bf(v.y); o.z = f2bf(v.z); o.w = f2bf(v.w);
    ((ushort4*)out)[i] = o;
}
// W (K x N f32) -> Wt (N x K bf16), LDS-tiled transpose: both sides coalesced.
// Grid: dim3(N/32, K/32), 256 threads (32x8). K,N are multiples of 32.
__global__ __launch_bounds__(256)
void wt_k(const float* __restrict__ w, unsigned short* __restrict__ wt, int K, int N) {
    __shared__ unsigned short t[32][33];
    const int bk = blockIdx.y * 32, bn = blockIdx.x * 32;
    const int tx = threadIdx.x & 31, ty = threadIdx.x >> 5;
#pragma unroll
    for (int r = 0; r < 32; r += 8)
        t[ty + r][tx] = f2bf(w[(size_t)(bk + ty + r) * N + bn + tx]);
    __syncthreads();
#pragma unroll
    for (int r = 0; r < 32; r += 8)
        wt[(size_t)(bn + ty + r) * K + bk + tx] = t[tx][ty + r];
}

// ---------------- CSR build ----------------
__global__ void zero_k(int* __restrict__ p, int n) {
    int i = blockIdx.x * 256 + threadIdx.x;
    if (i < n) p[i] = 0;
}
__global__ void hist_k(const int* __restrict__ ei, int* __restrict__ deg) {
    int e = blockIdx.x * 256 + threadIdx.x;
    if (e >= NE) return;
    atomicAdd(&deg[ei[NE + e]], 1);
}
// single-block exclusive scan over deg[NN] -> row_ptr, cursor
__global__ __launch_bounds__(1024)
void scan_k(const int* __restrict__ deg, int* __restrict__ row_ptr, int* __restrict__ cursor) {
    constexpr int T = 1024, C = (NN + T - 1) / T;  // 49
    const int tid = threadIdx.x;
    const int base = tid * C;
    int s = 0;
#pragma unroll 4
    for (int i = 0; i < C; ++i) {
        int idx = base + i;
        if (idx < NN) s += deg[idx];
    }
    __shared__ int sm[T];
    sm[tid] = s;
    __syncthreads();
    for (int off = 1; off < T; off <<= 1) {
        int v = (tid >= off) ? sm[tid - off] : 0;
        __syncthreads();
        sm[tid] += v;
        __syncthreads();
    }
    int run = (tid == 0) ? 0 : sm[tid - 1];
#pragma unroll 4
    for (int i = 0; i < C; ++i) {
        int idx = base + i;
        if (idx < NN) {
            row_ptr[idx] = run;
            cursor[idx] = run;
            run += deg[idx];
        }
    }
}
__global__ void build_col_k(const int* __restrict__ ei, int* __restrict__ cursor, int* __restrict__ col) {
    int e = blockIdx.x * 256 + threadIdx.x;
    if (e >= NE) return;
    int d = ei[NE + e];
    int p = atomicAdd(&cursor[d], 1);
    col[p] = ei[e];
}

// ---------------- gather-aggregate: z[n] = h[n] + sum_{j->n} h[j], bf16 out ----------------
template <int V> struct VecT;
template <> struct VecT<2> { using T = unsigned int; };
template <> struct VecT<4> { using T = uint2; };
template <> struct VecT<8> { using T = uint4; };

template <int D>
__global__ __launch_bounds__(256)
void agg_gather_k(const unsigned short* __restrict__ h,
                  const int* __restrict__ row_ptr, const int* __restrict__ deg,
                  const int* __restrict__ col, unsigned short* __restrict__ z) {
    constexpr int V = D / 64;
    using VT = typename VecT<V>::T;
    union U { VT v; unsigned short s[V]; };
    const int node = blockIdx.x * 4 + (threadIdx.x >> 6);
    if (node >= NN) return;
    const int lane = threadIdx.x & 63;
    const size_t fb = (size_t)lane * V;

    float acc[V];
    {
        U b; b.v = *(const VT*)(h + (size_t)node * D + fb);
#pragma unroll
        for (int i = 0; i < V; ++i) acc[i] = bf2f(b.s[i]);
    }
    const int s = row_ptr[node];
    const int e = s + deg[node];
    int t = s;
    for (; t + 2 <= e; t += 2) {
        int s0 = col[t], s1 = col[t + 1];
        U a0, a1;
        a0.v = *(const VT*)(h + (size_t)s0 * D + fb);
        a1.v = *(const VT*)(h + (size_t)s1 * D + fb);
#pragma unroll
        for (int i = 0; i < V; ++i) acc[i] += bf2f(a0.s[i]);
#pragma unroll
        for (int i = 0; i < V; ++i) acc[i] += bf2f(a1.s[i]);
    }
    if (t < e) {
        U a; a.v = *(const VT*)(h + (size_t)col[t] * D + fb);
#pragma unroll
        for (int i = 0; i < V; ++i) acc[i] += bf2f(a.s[i]);
    }
    U o;
#pragma unroll
    for (int i = 0; i < V; ++i) o.s[i] = f2bf(acc[i]);
    *(VT*)(z + (size_t)node * D + fb) = o.v;
}

// ---------------- MFMA GEMM building blocks (R1 structure: single-buffered) ----------------
// Stage a 128x64 bf16 tile (row stride = rstride shorts) into LDS via DMA.
// XOR swizzle folded into the per-lane SOURCE address: LDS slot s of row r
// holds k-block (s ^ (r&7)), matching the fragment-read addressing below.
static __device__ __forceinline__ void stage_tile128x64(
    const unsigned short* __restrict__ src, size_t rstride,
    unsigned short* lds, int wid, int lane) {
#pragma unroll
    for (int r = 0; r < 4; ++r) {
        const int rows8 = wid * 32 + r * 8;
        const int row = rows8 + (lane >> 3);
        const int kblk = (lane & 7) ^ (row & 7);
        __builtin_amdgcn_global_load_lds(
            (const __attribute__((address_space(1))) void*)(src + (size_t)row * rstride + (size_t)kblk * 8),
            (__attribute__((address_space(3))) void*)(lds + rows8 * 64),
            16, 0, 0);
    }
}

// XCD-aware bijective block swizzle (m204 formula), m-major logical order:
// each XCD gets a contiguous run of (m,n) tiles -> A panels fetched once per XCD L2.
#define GEMM_IDS(NT)                                                      \
    const int tid = threadIdx.x;                                          \
    const int lane = tid & 63;                                            \
    const int wid = tid >> 6;                                             \
    const int wm = wid & 1, wn = wid >> 1;                                \
    const int l15 = lane & 15, quad = lane >> 4;                          \
    int m0, n0;                                                           \
    {                                                                     \
        const int nwg = (int)(gridDim.x * gridDim.y);                     \
        const int orig = (int)(blockIdx.y * gridDim.x + blockIdx.x);      \
        const int q = nwg >> 3, r = nwg & 7;                              \
        const int xcd = orig & 7, idx = orig >> 3;                        \
        const int logical =                                               \
            (xcd < r ? xcd * (q + 1) : r * (q + 1) + (xcd - r) * q) + idx;\
        m0 = (logical / (NT)) * 128;                                      \
        n0 = (logical % (NT)) * 128;                                      \
    }

// R1 K-loop: stage -> syncthreads (drain) -> compute -> syncthreads.
// 32 KiB LDS + 64 VGPR -> ~3 blocks/CU; inter-block wave overlap hides staging (m114).
// NOTE: keep VGPR <= 64 -- occupancy cliff (R4: a 4-reg bias hoist cost 10%).
#define GEMM_KSTEP(AP, BP, KS)                                                        \
    for (int k0 = 0; k0 < (KS); k0 += 64) {                                           \
        stage_tile128x64((AP) + (size_t)m0 * (KS) + k0, (KS), lA, wid, lane);         \
        stage_tile128x64((BP) + (size_t)n0 * (KS) + k0, (KS), lB, wid, lane);         \
        __syncthreads();                                                              \
        _Pragma("unroll")                                                             \
        for (int kk = 0; kk < 2; ++kk) {                                              \
            short8 aF[4], bF[4];                                                      \
            _Pragma("unroll")                                                         \
            for (int i = 0; i < 4; ++i) {                                             \
                int ml = wm * 64 + i * 16 + l15;                                      \
                int kb = kk * 4 + quad;                                               \
                aF[i] = *(const short8*)&lA[(ml * 8 + (kb ^ (ml & 7))) * 8];          \
                int nl = wn * 64 + i * 16 + l15;                                      \
                bF[i] = *(const short8*)&lB[(nl * 8 + (kb ^ (nl & 7))) * 8];          \
            }                                                                         \
            _Pragma("unroll")                                                         \
            for (int i = 0; i < 4; ++i)                                               \
                _Pragma("unroll")                                                     \
                for (int j = 0; j < 4; ++j)                                           \
                    acc[i][j] = __builtin_amdgcn_mfma_f32_16x16x32_bf16(              \
                        aF[i], bF[j], acc[i][j], 0, 0, 0);                            \
        }                                                                             \
        __syncthreads();                                                              \
    }

// C = bf16(relu(A(MxK) * Bt(NxK)^T + bias))  -- first MLP layer
template <int K, int N>
__global__ __launch_bounds__(256, 2)
void gemm_relu_k(const unsigned short* __restrict__ A, const unsigned short* __restrict__ Bt,
                 const float* __restrict__ bias, unsigned short* __restrict__ outH, int M) {
    __shared__ unsigned short lA[128 * 64];
    __shared__ unsigned short lB[128 * 64];
    GEMM_IDS(N / 128)
    f32x4 acc[4][4];
#pragma unroll
    for (int i = 0; i < 4; ++i)
#pragma unroll
        for (int j = 0; j < 4; ++j) acc[i][j] = (f32x4){0.f, 0.f, 0.f, 0.f};

    GEMM_KSTEP(A, Bt, K)

#pragma unroll
    for (int i = 0; i < 4; ++i) {
#pragma unroll
        for (int j = 0; j < 4; ++j) {
            int col = n0 + wn * 64 + j * 16 + l15;
            float bv = bias[col];
#pragma unroll
            for (int r = 0; r < 4; ++r) {
                int row = m0 + wm * 64 + i * 16 + quad * 4 + r;
                if (row < M)
                    outH[(size_t)row * N + col] = f2bf(fmaxf(acc[i][j][r] + bv, 0.f));
            }
        }
    }
}

// out = relu( relu(A1*B1t^T + b1) + A2*B2t^T + b2 )  -- 2nd MLP layer + residual proj fused
// OUTBF16: write bf16 (consumed by bf16-input LN) instead of f32.
template <int K1, int K2, int N, bool OUTBF16>
__global__ __launch_bounds__(256, 2)
void gemm_fused_k(const unsigned short* __restrict__ A1, const unsigned short* __restrict__ B1t,
                  const float* __restrict__ b1,
                  const unsigned short* __restrict__ A2, const unsigned short* __restrict__ B2t,
                  const float* __restrict__ b2,
                  unsigned short* __restrict__ outH, float* __restrict__ outF, int M) {
    __shared__ unsigned short lA[128 * 64];
    __shared__ unsigned short lB[128 * 64];
    GEMM_IDS(N / 128)
    f32x4 acc[4][4];
#pragma unroll
    for (int i = 0; i < 4; ++i)
#pragma unroll
        for (int j = 0; j < 4; ++j) acc[i][j] = (f32x4){0.f, 0.f, 0.f, 0.f};

    GEMM_KSTEP(A1, B1t, K1)

    // in-register: acc = relu(acc + b1[col]); bias loaded HERE (between pipes),
    // not hoisted -- keeps VGPR at 64 (occupancy cliff, see R4 post-mortem)
#pragma unroll
    for (int j = 0; j < 4; ++j) {
        float bv = b1[n0 + wn * 64 + j * 16 + l15];
#pragma unroll
        for (int i = 0; i < 4; ++i)
#pragma unroll
            for (int r = 0; r < 4; ++r)
                acc[i][j][r] = fmaxf(acc[i][j][r] + bv, 0.f);
    }

    GEMM_KSTEP(A2, B2t, K2)

#pragma unroll
    for (int i = 0; i < 4; ++i) {
#pragma unroll
        for (int j = 0; j < 4; ++j) {
            int col = n0 + wn * 64 + j * 16 + l15;
            float bv = b2[col];
#pragma unroll
            for (int r = 0; r < 4; ++r) {
                int row = m0 + wm * 64 + i * 16 + quad * 4 + r;
                if (row < M) {
                    float v = fmaxf(acc[i][j][r] + bv, 0.f);
                    if constexpr (OUTBF16) outH[(size_t)row * N + col] = f2bf(v);
                    else                   outF[(size_t)row * N + col] = v;
                }
            }
        }
    }
}

// ---------------- LayerNorm: one block per row, vectorized contiguous loads ----------------
template <int D, bool INBF16, bool BF16OUT>
__global__ __launch_bounds__(256)
void ln_k(const unsigned short* __restrict__ tH, const float* __restrict__ tF,
          const float* __restrict__ g, const float* __restrict__ b,
          unsigned short* __restrict__ outH, float* __restrict__ outF) {
    constexpr int VPT = D / 256;
    const int row = blockIdx.x;
    const int tid = threadIdx.x;
    const int c0 = tid * VPT;
    float vals[VPT];
    // vectorized load of VPT contiguous elements
    if constexpr (INBF16) {
        const unsigned short* p = tH + (size_t)row * D + c0;
        if constexpr (VPT == 1) { vals[0] = bf2f(p[0]); }
        else if constexpr (VPT == 2) {
            ushort2 u = *(const ushort2*)p; vals[0] = bf2f(u.x); vals[1] = bf2f(u.y);
        } else {
            ushort4 u = *(const ushort4*)p;
            vals[0] = bf2f(u.x); vals[1] = bf2f(u.y); vals[2] = bf2f(u.z); vals[3] = bf2f(u.w);
        }
    } else {
        const float* p = tF + (size_t)row * D + c0;
        if constexpr (VPT == 1) { vals[0] = p[0]; }
        else if constexpr (VPT == 2) { float2 u = *(const float2*)p; vals[0] = u.x; vals[1] = u.y; }
        else { float4 u = *(const float4*)p; vals[0] = u.x; vals[1] = u.y; vals[2] = u.z; vals[3] = u.w; }
    }
    float s = 0.f, ss = 0.f;
#pragma unroll
    for (int i = 0; i < VPT; ++i) { s += vals[i]; ss += vals[i] * vals[i]; }
#pragma unroll
    for (int off = 32; off; off >>= 1) { s += __shfl_down(s, off); ss += __shfl_down(ss, off); }
    __shared__ float ps[4], pss[4];
    int lane = tid & 63, wv = tid >> 6;
    if (lane == 0) { ps[wv] = s; pss[wv] = ss; }
    __syncthreads();
    float st = ps[0] + ps[1] + ps[2] + ps[3];
    float sst = pss[0] + pss[1] + pss[2] + pss[3];
    float mean = st / D;
    float var = sst / D - mean * mean;
    float inv = rsqrtf(var + 1e-5f);
    float outv[VPT];
#pragma unroll
    for (int i = 0; i < VPT; ++i)
        outv[i] = (vals[i] - mean) * inv * g[c0 + i] + b[c0 + i];
    if constexpr (BF16OUT) {
        unsigned short* p = outH + (size_t)row * D + c0;
        if constexpr (VPT == 1) { p[0] = f2bf(outv[0]); }
        else if constexpr (VPT == 2) {
            ushort2 u; u.x = f2bf(outv[0]); u.y = f2bf(outv[1]); *(ushort2*)p = u;
        } else {
            ushort4 u; u.x = f2bf(outv[0]); u.y = f2bf(outv[1]); u.z = f2bf(outv[2]); u.w = f2bf(outv[3]);
            *(ushort4*)p = u;
        }
    } else {
        float* p = outF + (size_t)row * D + c0;
        if constexpr (VPT == 1) { p[0] = outv[0]; }
        else if constexpr (VPT == 2) { float2 u; u.x = outv[0]; u.y = outv[1]; *(float2*)p = u; }
        else { float4 u; u.x = outv[0]; u.y = outv[1]; u.z = outv[2]; u.w = outv[3]; *(float4*)p = u; }
    }
}

static inline int cdiv(long a, long b) { return (int)((a + b - 1) / b); }

extern "C" void kernel_launch(void* const* d_in, const int* in_sizes, int n_in,
                              void* d_out, int out_size, void* d_ws, size_t ws_size,
                              hipStream_t stream) {
    const float* x   = (const float*)d_in[0];
    const int*   ei  = (const int*)  d_in[1];
    const float* w1a = (const float*)d_in[2],  *b1a = (const float*)d_in[3];
    const float* w1b = (const float*)d_in[4],  *b1b = (const float*)d_in[5];
    const float* w2a = (const float*)d_in[6],  *b2a = (const float*)d_in[7];
    const float* w2b = (const float*)d_in[8],  *b2b = (const float*)d_in[9];
    const float* w3a = (const float*)d_in[10], *b3a = (const float*)d_in[11];
    const float* w3b = (const float*)d_in[12], *b3b = (const float*)d_in[13];
    const float* rp1 = (const float*)d_in[14], *rp1b = (const float*)d_in[15];
    const float* rp2 = (const float*)d_in[16], *rp2b = (const float*)d_in[17];
    const float* rp3 = (const float*)d_in[18], *rp3b = (const float*)d_in[19];
    const float* g1 = (const float*)d_in[20], *be1 = (const float*)d_in[21];
    const float* g2 = (const float*)d_in[22], *be2 = (const float*)d_in[23];
    const float* g3 = (const float*)d_in[24], *be3 = (const float*)d_in[25];

    char* ws = (char*)d_ws;
    size_t off = 0;
    auto alloc = [&](size_t n) { char* p = ws + off; off += (n + 255) & ~(size_t)255; return p; };
    unsigned short* w1aT = (unsigned short*)alloc((size_t)128 * 256 * 2);
    unsigned short* w1bT = (unsigned short*)alloc((size_t)256 * 256 * 2);
    unsigned short* w2aT = (unsigned short*)alloc((size_t)256 * 512 * 2);
    unsigned short* w2bT = (unsigned short*)alloc((size_t)512 * 512 * 2);
    unsigned short* w3aT = (unsigned short*)alloc((size_t)512 * 1024 * 2);
    unsigned short* w3bT = (unsigned short*)alloc((size_t)1024 * 1024 * 2);
    unsigned short* rp1T = (unsigned short*)alloc((size_t)128 * 256 * 2);
    unsigned short* rp2T = (unsigned short*)alloc((size_t)256 * 512 * 2);
    unsigned short* rp3T = (unsigned short*)alloc((size_t)512 * 1024 * 2);
    unsigned short* hA  = (unsigned short*)alloc((size_t)M_PAD * 512 * 2);
    unsigned short* hB  = (unsigned short*)alloc((size_t)M_PAD * 512 * 2);
    unsigned short* zin = (unsigned short*)alloc((size_t)M_PAD * 512 * 2);
    unsigned short* z1  = (unsigned short*)alloc((size_t)M_PAD * 1024 * 2);
    float* resb = (float*)alloc((size_t)M_PAD * 1024 * 4);
    int* deg     = (int*)alloc((size_t)NN * 4);
    int* row_ptr = (int*)alloc((size_t)NN * 4);
    int* cursor  = (int*)alloc((size_t)NN * 4);
    int* colv    = (int*)alloc((size_t)NE * 4);
    (void)ws_size; (void)in_sizes; (void)n_in; (void)out_size;

    // ---- CSR build (shared by all 3 blocks) ----
    zero_k<<<cdiv(NN, 256), 256, 0, stream>>>(deg, NN);
    hist_k<<<cdiv(NE, 256), 256, 0, stream>>>(ei, deg);
    scan_k<<<1, 1024, 0, stream>>>(deg, row_ptr, cursor);
    build_col_k<<<cdiv(NE, 256), 256, 0, stream>>>(ei, cursor, colv);

    // ---- weights -> bf16 transposed (N x K), LDS-tiled ----
    wt_k<<<dim3(256 / 32, 128 / 32), 256, 0, stream>>>(w1a, w1aT, 128, 256);
    wt_k<<<dim3(256 / 32, 256 / 32), 256, 0, stream>>>(w1b, w1bT, 256, 256);
    wt_k<<<dim3(512 / 32, 256 / 32), 256, 0, stream>>>(w2a, w2aT, 256, 512);
    wt_k<<<dim3(512 / 32, 512 / 32), 256, 0, stream>>>(w2b, w2bT, 512, 512);
    wt_k<<<dim3(1024 / 32, 512 / 32), 256, 0, stream>>>(w3a, w3aT, 512, 1024);
    wt_k<<<dim3(1024 / 32, 1024 / 32), 256, 0, stream>>>(w3b, w3bT, 1024, 1024);
    wt_k<<<dim3(256 / 32, 128 / 32), 256, 0, stream>>>(rp1, rp1T, 128, 256);
    wt_k<<<dim3(512 / 32, 256 / 32), 256, 0, stream>>>(rp2, rp2T, 256, 512);
    wt_k<<<dim3(1024 / 32, 512 / 32), 256, 0, stream>>>(rp3, rp3T, 512, 1024);

    // x -> bf16
    f32_to_bf16_k<<<cdiv((long)NN * 128 / 4, 256), 256, 0, stream>>>(x, hA, (long)NN * 128 / 4);

    // ---- block 1: Din=128, Dout=256, h = hA ----
    agg_gather_k<128><<<cdiv(NN, 4), 256, 0, stream>>>(hA, row_ptr, deg, colv, zin);
    gemm_relu_k<128, 256><<<dim3(2, 391), 256, 0, stream>>>(zin, w1aT, b1a, z1, NN);
    // fused out -> bf16, reuse zin (gemm_relu consumed it)
    gemm_fused_k<256, 128, 256, true><<<dim3(2, 391), 256, 0, stream>>>(
        z1, w1bT, b1b, hA, rp1T, rp1b, zin, nullptr, NN);
    ln_k<256, true, true><<<NN, 256, 0, stream>>>(zin, nullptr, g1, be1, hB, nullptr);

    // ---- block 2: Din=256, Dout=512, h = hB ----
    agg_gather_k<256><<<cdiv(NN, 4), 256, 0, stream>>>(hB, row_ptr, deg, colv, zin);
    gemm_relu_k<256, 512><<<dim3(4, 391), 256, 0, stream>>>(zin, w2aT, b2a, z1, NN);
    gemm_fused_k<512, 256, 512, true><<<dim3(4, 391), 256, 0, stream>>>(
        z1, w2bT, b2b, hB, rp2T, rp2b, zin, nullptr, NN);
    ln_k<512, true, true><<<NN, 256, 0, stream>>>(zin, nullptr, g2, be2, hA, nullptr);

    // ---- block 3: Din=512, Dout=1024, h = hA ----
    agg_gather_k<512><<<cdiv(NN, 4), 256, 0, stream>>>(hA, row_ptr, deg, colv, zin);
    gemm_relu_k<512, 1024><<<dim3(8, 391), 256, 0, stream>>>(zin, w3aT, b3a, z1, NN);
    // b3 fused out -> bf16 into resb's space (error dominated by bf16 GEMM inputs;
    // absmax was invariant under the same change on blocks 1/2)
    gemm_fused_k<1024, 512, 1024, true><<<dim3(8, 391), 256, 0, stream>>>(
        z1, w3bT, b3b, hA, rp3T, rp3b, (unsigned short*)resb, nullptr, NN);
    ln_k<1024, true, false><<<NN, 256, 0, stream>>>((unsigned short*)resb, nullptr, g3, be3, nullptr, (float*)d_out);
}